// Round 1
// baseline (277.669 us; speedup 1.0000x reference)
//
#include <hip/hip_runtime.h>
#include <hip/hip_bf16.h>

// MultiHeadSelfAttention: B=2, S=2048, D=1024, H=16, DK=64
// Pipeline: cast/transpose -> QKV GEMM (bf16 MFMA) -> flash attention -> out GEMM fused epilogue.

using bf16 = __hip_bfloat16;
typedef __attribute__((ext_vector_type(8))) short bf16x8;   // 8 bf16 = 4 VGPRs
typedef __attribute__((ext_vector_type(4))) float f32x4;

static __device__ __forceinline__ f32x4 mfma_bf16(bf16x8 a, bf16x8 b, f32x4 c) {
    return __builtin_amdgcn_mfma_f32_16x16x32_bf16(a, b, c, 0, 0, 0);
}

// ---------------- cast x (fp32 -> bf16), vectorized ----------------
__global__ void cast_bf16_kernel(const float* __restrict__ in, bf16* __restrict__ out, int n4) {
    int i = blockIdx.x * blockDim.x + threadIdx.x;
    if (i >= n4) return;
    float4 f = reinterpret_cast<const float4*>(in)[i];
    out[4*i+0] = __float2bfloat16(f.x);
    out[4*i+1] = __float2bfloat16(f.y);
    out[4*i+2] = __float2bfloat16(f.z);
    out[4*i+3] = __float2bfloat16(f.w);
}

// ---------------- transpose + cast: in fp32 [R][C] -> out bf16 [C][R] ----------------
__global__ void transpose_cast_kernel(const float* __restrict__ in, bf16* __restrict__ out,
                                      int R, int C) {
    __shared__ float tile[32][33];
    int c0 = blockIdx.x * 32, r0 = blockIdx.y * 32;
    int x = threadIdx.x, y = threadIdx.y;   // block (32,8)
#pragma unroll
    for (int i = 0; i < 32; i += 8) tile[y + i][x] = in[(size_t)(r0 + y + i) * C + c0 + x];
    __syncthreads();
#pragma unroll
    for (int i = 0; i < 32; i += 8)
        out[(size_t)(c0 + y + i) * R + r0 + x] = __float2bfloat16(tile[x][y + i]);
}

// ---------------- GEMM: C[M,N] = A[M,K] @ Bt[N,K]^T  (bf16 in, fp32 acc) ----------------
// 128x128 block tile, BK=64, 4 waves in 2x2, each wave 4x4 MFMA tiles of 16x16x32.
// EPI=0: QKV epilogue (bias add, scatter to per-head Q/K/Vt bf16)
// EPI=1: out epilogue  (bias add, *(gamma+1), fp32 store)
template <int EPI>
__global__ __launch_bounds__(256, 2)
void gemm_bt_kernel(const bf16* __restrict__ A, const bf16* __restrict__ Bt,
                    int M, int N, int K,
                    const float* __restrict__ bias, const float* __restrict__ gamma,
                    bf16* __restrict__ Qout, bf16* __restrict__ Kout, bf16* __restrict__ Vtout,
                    float* __restrict__ Cout) {
    __shared__ bf16 As[128 * 72];   // padded stride 72 (2-way bank alias only)
    __shared__ bf16 Bs[128 * 72];

    const int tid  = threadIdx.x;
    const int wave = tid >> 6, lane = tid & 63;
    const int quad = lane >> 4, l16 = lane & 15;
    const int wr = wave >> 1, wc = wave & 1;
    const int bm = blockIdx.y, bn = blockIdx.x;

    f32x4 acc[4][4] = {};

    // staging: thread t -> row t>>1 (0..127), half t&1 -> 32 bf16 = 64 B = 4x uint4
    const int srow = tid >> 1, shalf = tid & 1;
    const bf16* gA = A  + (size_t)(bm * 128 + srow) * K + shalf * 32;
    const bf16* gB = Bt + (size_t)(bn * 128 + srow) * K + shalf * 32;
    uint4* lA = (uint4*)(As + srow * 72 + shalf * 32);
    uint4* lB = (uint4*)(Bs + srow * 72 + shalf * 32);

    for (int k0 = 0; k0 < K; k0 += 64) {
        const uint4* ga = (const uint4*)(gA + k0);
        const uint4* gb = (const uint4*)(gB + k0);
        uint4 a0 = ga[0], a1 = ga[1], a2 = ga[2], a3 = ga[3];
        uint4 b0 = gb[0], b1 = gb[1], b2 = gb[2], b3 = gb[3];
        lA[0] = a0; lA[1] = a1; lA[2] = a2; lA[3] = a3;
        lB[0] = b0; lB[1] = b1; lB[2] = b2; lB[3] = b3;
        __syncthreads();
#pragma unroll
        for (int ks = 0; ks < 2; ++ks) {
            bf16x8 af[4], bfr[4];
#pragma unroll
            for (int mi = 0; mi < 4; ++mi)
                af[mi] = *(const bf16x8*)(As + (wr * 64 + mi * 16 + l16) * 72 + ks * 32 + quad * 8);
#pragma unroll
            for (int ni = 0; ni < 4; ++ni)
                bfr[ni] = *(const bf16x8*)(Bs + (wc * 64 + ni * 16 + l16) * 72 + ks * 32 + quad * 8);
#pragma unroll
            for (int mi = 0; mi < 4; ++mi)
#pragma unroll
                for (int ni = 0; ni < 4; ++ni)
                    acc[mi][ni] = mfma_bf16(af[mi], bfr[ni], acc[mi][ni]);
        }
        __syncthreads();
    }

    // epilogue: C[row=quad*4+r][col=l16] per 16x16 tile (verified gfx950 C/D layout)
#pragma unroll
    for (int mi = 0; mi < 4; ++mi) {
#pragma unroll
        for (int ni = 0; ni < 4; ++ni) {
#pragma unroll
            for (int r = 0; r < 4; ++r) {
                int row = bm * 128 + wr * 64 + mi * 16 + quad * 4 + r;
                int col = bn * 128 + wc * 64 + ni * 16 + l16;
                float v = acc[mi][ni][r];
                if (EPI == 0) {
                    v += bias[col];
                    // per-head interleaved split: (H, 3*DK) over the 3072 cols
                    int h = col / 192;
                    int rr = col - h * 192;
                    int which = rr >> 6, dk = rr & 63;
                    int b = row >> 11, s = row & 2047;   // S = 2048
                    size_t bh = (size_t)b * 16 + h;
                    bf16 bv = __float2bfloat16(v);
                    if (which == 0)      Qout[(bh * 2048 + s) * 64 + dk] = bv;
                    else if (which == 1) Kout[(bh * 2048 + s) * 64 + dk] = bv;
                    else                 Vtout[(bh * 64 + dk) * 2048 + s] = bv;
                } else {
                    float o = (gamma[col] + 1.0f) * (v + bias[col]);
                    Cout[(size_t)row * N + col] = o;
                }
            }
        }
    }
}

// ---------------- flash attention ----------------
// grid: (S/64, B*H). block 256 = 4 waves; wave w owns q rows [q0+16w, q0+16w+16).
__global__ __launch_bounds__(256, 4)
void attn_kernel(const bf16* __restrict__ Qb, const bf16* __restrict__ Kb,
                 const bf16* __restrict__ Vt, const int* __restrict__ mask,
                 bf16* __restrict__ Aout) {
    __shared__ bf16 Ks[64 * 72];      // K tile: [kpos][dk]
    __shared__ bf16 Vs[64 * 72];      // V tile transposed: [dk][kpos]
    __shared__ bf16 Ps[4][16 * 72];   // per-wave P tile: [qrow 0..15][kpos 0..63]

    const int bh = blockIdx.y;
    const int b = bh >> 4, h = bh & 15;
    const int q0 = blockIdx.x * 64;
    const int tid = threadIdx.x;
    const int wave = tid >> 6, lane = tid & 63;
    const int quad = lane >> 4, l16 = lane & 15;
    const float scale = 0.125f;   // 1/sqrt(64)

    // Q A-fragments (constant over k loop): A[m=l16][k=quad*8+j (+32*ks)]
    const int qrow = q0 + wave * 16 + l16;
    const bf16* qptr = Qb + ((size_t)bh * 2048 + qrow) * 64;
    bf16x8 aq0 = *(const bf16x8*)(qptr + quad * 8);
    bf16x8 aq1 = *(const bf16x8*)(qptr + 32 + quad * 8);

    float m_i[4], l_i[4];
    f32x4 O[4] = {};
#pragma unroll
    for (int r = 0; r < 4; ++r) { m_i[r] = -1e30f; l_i[r] = 0.0f; }

    // staging: thread t -> row t>>2 (0..63), part t&3 -> 16 bf16 = 2x uint4
    const int srow = tid >> 2, spart = tid & 3;
    const bf16* gK = Kb + ((size_t)bh * 2048 + srow) * 64 + spart * 16;
    const bf16* gV = Vt + ((size_t)bh * 64 + srow) * 2048 + spart * 16;
    uint4* lK = (uint4*)(Ks + srow * 72 + spart * 16);
    uint4* lV = (uint4*)(Vs + srow * 72 + spart * 16);
    bf16* myPs = &Ps[wave][0];

    for (int kt = 0; kt < 32; ++kt) {
        const uint4* ga = (const uint4*)(gK + (size_t)kt * 64 * 64);
        const uint4* gv = (const uint4*)(gV + kt * 64);
        uint4 k0v = ga[0], k1v = ga[1];
        uint4 v0v = gv[0], v1v = gv[1];
        lK[0] = k0v; lK[1] = k1v;
        lV[0] = v0v; lV[1] = v1v;
        __syncthreads();

        // S = Q K^T for this wave's 16 rows x 64 cols
        float xv[4][4];
        const int kbase = kt * 64;
#pragma unroll
        for (int nt = 0; nt < 4; ++nt) {
            const bf16* kp = Ks + (nt * 16 + l16) * 72 + quad * 8;
            bf16x8 bk0 = *(const bf16x8*)kp;
            bf16x8 bk1 = *(const bf16x8*)(kp + 32);
            f32x4 c = {0.f, 0.f, 0.f, 0.f};
            c = mfma_bf16(aq0, bk0, c);
            c = mfma_bf16(aq1, bk1, c);
            int kpos = kbase + nt * 16 + l16;
            int mv = mask[b * 2048 + kpos];
#pragma unroll
            for (int r = 0; r < 4; ++r) xv[nt][r] = (mv != 0) ? c[r] * scale : -1e30f;
        }

        // online softmax (row = quad*4+r; reduce across the 16-lane col group)
        float tmax[4];
#pragma unroll
        for (int r = 0; r < 4; ++r) {
            tmax[r] = fmaxf(fmaxf(xv[0][r], xv[1][r]), fmaxf(xv[2][r], xv[3][r]));
            tmax[r] = fmaxf(tmax[r], __shfl_xor(tmax[r], 1, 64));
            tmax[r] = fmaxf(tmax[r], __shfl_xor(tmax[r], 2, 64));
            tmax[r] = fmaxf(tmax[r], __shfl_xor(tmax[r], 4, 64));
            tmax[r] = fmaxf(tmax[r], __shfl_xor(tmax[r], 8, 64));
        }
        float alpha[4], rs[4];
#pragma unroll
        for (int r = 0; r < 4; ++r) {
            float mn = fmaxf(m_i[r], tmax[r]);
            alpha[r] = __expf(m_i[r] - mn);
            m_i[r] = mn;
            rs[r] = 0.0f;
        }
#pragma unroll
        for (int nt = 0; nt < 4; ++nt) {
#pragma unroll
            for (int r = 0; r < 4; ++r) {
                float p = __expf(xv[nt][r] - m_i[r]);
                rs[r] += p;
                myPs[(quad * 4 + r) * 72 + nt * 16 + l16] = __float2bfloat16(p);
            }
        }
#pragma unroll
        for (int r = 0; r < 4; ++r) {
            rs[r] += __shfl_xor(rs[r], 1, 64);
            rs[r] += __shfl_xor(rs[r], 2, 64);
            rs[r] += __shfl_xor(rs[r], 4, 64);
            rs[r] += __shfl_xor(rs[r], 8, 64);
            l_i[r] = l_i[r] * alpha[r] + rs[r];
        }
#pragma unroll
        for (int nt = 0; nt < 4; ++nt)
#pragma unroll
            for (int r = 0; r < 4; ++r) O[nt][r] *= alpha[r];

        // O += P V  (P via LDS round-trip C-layout -> A-layout; V transposed in LDS)
#pragma unroll
        for (int ks = 0; ks < 2; ++ks) {
            bf16x8 ap = *(const bf16x8*)(myPs + l16 * 72 + ks * 32 + quad * 8);
#pragma unroll
            for (int nt = 0; nt < 4; ++nt) {
                bf16x8 bv = *(const bf16x8*)(Vs + (nt * 16 + l16) * 72 + ks * 32 + quad * 8);
                O[nt] = mfma_bf16(ap, bv, O[nt]);
            }
        }
        __syncthreads();
    }

    // write attention output (b, s, h*64+dk) as bf16
    const int orow = q0 + wave * 16;
#pragma unroll
    for (int nt = 0; nt < 4; ++nt) {
#pragma unroll
        for (int r = 0; r < 4; ++r) {
            float v = O[nt][r] / l_i[r];
            int row = orow + quad * 4 + r;
            Aout[((size_t)b * 2048 + row) * 1024 + h * 64 + nt * 16 + l16] = __float2bfloat16(v);
        }
    }
}

// ---------------- launcher ----------------
extern "C" void kernel_launch(void* const* d_in, const int* in_sizes, int n_in,
                              void* d_out, int out_size, void* d_ws, size_t ws_size,
                              hipStream_t stream) {
    const float* x     = (const float*)d_in[0];
    const float* gamma = (const float*)d_in[1];
    const int*   mask  = (const int*)d_in[2];
    const float* wqkv  = (const float*)d_in[3];
    const float* bqkv  = (const float*)d_in[4];
    const float* wo    = (const float*)d_in[5];
    const float* bo    = (const float*)d_in[6];
    float* out = (float*)d_out;

    char* ws = (char*)d_ws;
    const size_t MB = 1u << 20;
    bf16* xb    = (bf16*)(ws);            //  8 MB: x cast to bf16      [4096][1024]
    bf16* wqkvT = (bf16*)(ws + 8 * MB);   //  6 MB: W_qkv^T bf16        [3072][1024]
    bf16* woT   = (bf16*)(ws + 14 * MB);  //  2 MB: W_o^T bf16          [1024][1024]
    bf16* Qb    = (bf16*)(ws + 16 * MB);  //  8 MB: Q per head          [bh][s][dk]
    bf16* Kb    = (bf16*)(ws + 24 * MB);  //  8 MB: K per head          [bh][s][dk]
    bf16* Vt    = (bf16*)(ws + 32 * MB);  //  8 MB: V^T per head        [bh][dk][s]
    bf16* attn  = (bf16*)(ws + 40 * MB);  //  8 MB: attention out       [b*s][d]

    cast_bf16_kernel<<<4096, 256, 0, stream>>>(x, xb, 4194304 / 4);
    transpose_cast_kernel<<<dim3(96, 32), dim3(32, 8), 0, stream>>>(wqkv, wqkvT, 1024, 3072);
    transpose_cast_kernel<<<dim3(32, 32), dim3(32, 8), 0, stream>>>(wo, woT, 1024, 1024);

    // QKV GEMM: [4096,1024] x [1024,3072]
    gemm_bt_kernel<0><<<dim3(24, 32), 256, 0, stream>>>(
        xb, wqkvT, 4096, 3072, 1024, bqkv, nullptr, Qb, Kb, Vt, nullptr);

    // attention: grid (S/64, B*H)
    attn_kernel<<<dim3(32, 32), 256, 0, stream>>>(Qb, Kb, Vt, mask, attn);

    // out GEMM: [4096,1024] x [1024,1024], fused bias + (gamma+1)
    gemm_bt_kernel<1><<<dim3(8, 32), 256, 0, stream>>>(
        attn, woT, 4096, 1024, 1024, bo, gamma, nullptr, nullptr, nullptr, out);
}

// Round 2
// 211.921 us; speedup vs baseline: 1.3102x; 1.3102x over previous
//
#include <hip/hip_runtime.h>
#include <hip/hip_bf16.h>

// MultiHeadSelfAttention: B=2, S=2048, D=1024, H=16, DK=64
// R2: (a) attn rewritten with static-max softmax (no online max/rescale; l via
//     ones-MFMA; Q pre-scaled by scale*log2e so p = exp2(c + bias)), q-tile 128,
//     reg-prefetch double buffering.
//     (b) GEMMs use global_load_lds width=16 (m97 pattern) with XOR-swizzled
//     source blocks so unpadded stride-64 LDS reads are ~conflict-free.

using bf16 = __hip_bfloat16;
typedef __attribute__((ext_vector_type(8))) short bf16x8;   // 8 bf16 = 4 VGPRs
typedef __attribute__((ext_vector_type(4))) float f32x4;

#define QSCALE 0.18033688011112042f   // (1/sqrt(64)) * log2(e)

static __device__ __forceinline__ f32x4 mfma_bf16(bf16x8 a, bf16x8 b, f32x4 c) {
    return __builtin_amdgcn_mfma_f32_16x16x32_bf16(a, b, c, 0, 0, 0);
}

// async global -> LDS, 16 bytes per lane; lane l deposits at ldsbase + 16*l.
static __device__ __forceinline__ void gld_lds16(const void* g, void* s) {
    __builtin_amdgcn_global_load_lds(
        (const __attribute__((address_space(1))) unsigned int*)g,
        (__attribute__((address_space(3))) unsigned int*)s,
        16, 0, 0);
}

// ---------------- cast x (fp32 -> bf16), vectorized ----------------
__global__ void cast_bf16_kernel(const float* __restrict__ in, bf16* __restrict__ out, int n4) {
    int i = blockIdx.x * blockDim.x + threadIdx.x;
    if (i >= n4) return;
    float4 f = reinterpret_cast<const float4*>(in)[i];
    out[4*i+0] = __float2bfloat16(f.x);
    out[4*i+1] = __float2bfloat16(f.y);
    out[4*i+2] = __float2bfloat16(f.z);
    out[4*i+3] = __float2bfloat16(f.w);
}

// ---------------- transpose + cast: in fp32 [R][C] -> out bf16 [C][R] ----------------
__global__ void transpose_cast_kernel(const float* __restrict__ in, bf16* __restrict__ out,
                                      int R, int C) {
    __shared__ float tile[32][33];
    int c0 = blockIdx.x * 32, r0 = blockIdx.y * 32;
    int x = threadIdx.x, y = threadIdx.y;   // block (32,8)
#pragma unroll
    for (int i = 0; i < 32; i += 8) tile[y + i][x] = in[(size_t)(r0 + y + i) * C + c0 + x];
    __syncthreads();
#pragma unroll
    for (int i = 0; i < 32; i += 8)
        out[(size_t)(c0 + y + i) * R + r0 + x] = __float2bfloat16(tile[x][y + i]);
}

// ---------------- GEMM: C[M,N] = A[M,K] @ Bt[N,K]^T  (bf16 in, fp32 acc) ----------------
// 128x128 tile, BK=64, 4 waves 2x2, each wave 4x4 MFMA of 16x16x32.
// Staging via global_load_lds dwordx4; LDS unpadded stride 64, XOR source swizzle:
// LDS (row r, 16B-block p) holds global block p ^ (r&7).
template <int EPI>
__global__ __launch_bounds__(256, 2)
void gemm_bt_kernel(const bf16* __restrict__ A, const bf16* __restrict__ Bt,
                    int M, int N, int K,
                    const float* __restrict__ bias, const float* __restrict__ gamma,
                    bf16* __restrict__ Qout, bf16* __restrict__ Kout, bf16* __restrict__ Vtout,
                    float* __restrict__ Cout) {
    __shared__ __align__(16) bf16 As[128 * 64];
    __shared__ __align__(16) bf16 Bs[128 * 64];

    const int tid  = threadIdx.x;
    const int wave = tid >> 6, lane = tid & 63;
    const int quad = lane >> 4, l16 = lane & 15;
    const int wr = wave >> 1, wc = wave & 1;
    const int bm = blockIdx.y, bn = blockIdx.x;

    f32x4 acc[4][4] = {};

    // staging: wave w stages rows [w*32, w*32+32) as 4 chunks of 1024B (8 rows each).
    // lane l -> row (l>>3) in chunk, stored block (l&7) holding source block (l&7)^(l>>3 &7).
    const int crow = lane >> 3;
    const int sblk = (lane & 7) ^ (crow & 7);
    const bf16* gA[4]; const bf16* gB[4]; bf16* lA[4]; bf16* lB[4];
#pragma unroll
    for (int c = 0; c < 4; ++c) {
        int rt = wave * 32 + c * 8 + crow;
        gA[c] = A  + (size_t)(bm * 128 + rt) * K + sblk * 8;
        gB[c] = Bt + (size_t)(bn * 128 + rt) * K + sblk * 8;
        lA[c] = As + (wave * 4 + c) * 512 + lane * 8;
        lB[c] = Bs + (wave * 4 + c) * 512 + lane * 8;
    }
    const int xr = l16 & 7;

    for (int k0 = 0; k0 < K; k0 += 64) {
#pragma unroll
        for (int c = 0; c < 4; ++c) gld_lds16(gA[c] + k0, lA[c]);
#pragma unroll
        for (int c = 0; c < 4; ++c) gld_lds16(gB[c] + k0, lB[c]);
        __syncthreads();
#pragma unroll
        for (int ks = 0; ks < 2; ++ks) {
            bf16x8 af[4], bfr[4];
#pragma unroll
            for (int mi = 0; mi < 4; ++mi)
                af[mi] = *(const bf16x8*)(As + (wr * 64 + mi * 16 + l16) * 64 + ((4 * ks + quad) ^ xr) * 8);
#pragma unroll
            for (int ni = 0; ni < 4; ++ni)
                bfr[ni] = *(const bf16x8*)(Bs + (wc * 64 + ni * 16 + l16) * 64 + ((4 * ks + quad) ^ xr) * 8);
#pragma unroll
            for (int mi = 0; mi < 4; ++mi)
#pragma unroll
                for (int ni = 0; ni < 4; ++ni)
                    acc[mi][ni] = mfma_bf16(af[mi], bfr[ni], acc[mi][ni]);
        }
        __syncthreads();
    }

    // epilogue: C[row=quad*4+r][col=l16] per 16x16 tile
#pragma unroll
    for (int mi = 0; mi < 4; ++mi) {
#pragma unroll
        for (int ni = 0; ni < 4; ++ni) {
#pragma unroll
            for (int r = 0; r < 4; ++r) {
                int row = bm * 128 + wr * 64 + mi * 16 + quad * 4 + r;
                int col = bn * 128 + wc * 64 + ni * 16 + l16;
                float v = acc[mi][ni][r];
                if (EPI == 0) {
                    v += bias[col];
                    int h = col / 192;
                    int rr = col - h * 192;
                    int which = rr >> 6, dk = rr & 63;
                    int b = row >> 11, s = row & 2047;   // S = 2048
                    size_t bh = (size_t)b * 16 + h;
                    if (which == 0) {
                        // fold scale*log2e into Q for the static-max softmax
                        Qout[(bh * 2048 + s) * 64 + dk] = __float2bfloat16(v * QSCALE);
                    } else if (which == 1) {
                        Kout[(bh * 2048 + s) * 64 + dk] = __float2bfloat16(v);
                    } else {
                        Vtout[(bh * 64 + dk) * 2048 + s] = __float2bfloat16(v);
                    }
                } else {
                    float o = (gamma[col] + 1.0f) * (v + bias[col]);
                    Cout[(size_t)row * N + col] = o;
                }
            }
        }
    }
}

// ---------------- flash attention, static-max softmax ----------------
// grid: (S/128, B*H). block 256 = 4 waves; wave w owns q rows [q0+32w, q0+32w+32)
// as two 16-row MFMA m-groups. K-tile = 64. p = exp2(c + bias[col]) where Q was
// pre-scaled by scale*log2e and bias = mask? -24 : -1e30. Row-sum l accumulated
// by MFMA against a ones B-fragment (all-equal columns).
__global__ __launch_bounds__(256, 2)
void attn_kernel(const bf16* __restrict__ Qb, const bf16* __restrict__ Kb,
                 const bf16* __restrict__ Vt, const int* __restrict__ mask,
                 bf16* __restrict__ Aout) {
    __shared__ __align__(16) bf16 Ks[64 * 72];      // K tile: [kpos][dk]
    __shared__ __align__(16) bf16 Vs[64 * 72];      // V tile transposed: [dk][kpos]
    __shared__ __align__(16) bf16 Ps[4][32 * 72];   // per-wave P: [qrow 0..31][kpos 0..63]
    __shared__ float Biass[64];

    const int bh = blockIdx.y;
    const int b = bh >> 4, h = bh & 15;
    const int q0 = blockIdx.x * 128;
    const int tid = threadIdx.x;
    const int wave = tid >> 6, lane = tid & 63;
    const int quad = lane >> 4, l16 = lane & 15;

    // Q A-fragments (constant over k loop)
    bf16x8 aq[2][2];
#pragma unroll
    for (int m = 0; m < 2; ++m) {
        const bf16* qp = Qb + ((size_t)bh * 2048 + q0 + wave * 32 + m * 16 + l16) * 64;
        aq[m][0] = *(const bf16x8*)(qp + quad * 8);
        aq[m][1] = *(const bf16x8*)(qp + 32 + quad * 8);
    }

    bf16x8 ones;
#pragma unroll
    for (int j = 0; j < 8; ++j) ones[j] = (short)0x3F80;   // bf16 1.0

    f32x4 O[2][4] = {};
    f32x4 Lacc[2] = {};

    // staging: thread t -> row t>>2 (0..63), part t&3 -> 16 bf16 = 2x uint4
    const int srow = tid >> 2, spart = tid & 3;
    const bf16* gK = Kb + ((size_t)bh * 2048 + srow) * 64 + spart * 16;
    const bf16* gV = Vt + ((size_t)bh * 64 + srow) * 2048 + spart * 16;
    uint4* lK = (uint4*)(Ks + srow * 72 + spart * 16);
    uint4* lV = (uint4*)(Vs + srow * 72 + spart * 16);
    bf16* myPs = &Ps[wave][0];

    // prefetch tile 0
    uint4 kr0, kr1, vr0, vr1; int mreg = 1;
    {
        const uint4* nk = (const uint4*)gK;
        const uint4* nv = (const uint4*)gV;
        kr0 = nk[0]; kr1 = nk[1];
        vr0 = nv[0]; vr1 = nv[1];
        if (tid < 64) mreg = mask[b * 2048 + tid];
    }

    for (int kt = 0; kt < 32; ++kt) {
        lK[0] = kr0; lK[1] = kr1;
        lV[0] = vr0; lV[1] = vr1;
        if (tid < 64) Biass[tid] = mreg ? -24.0f : -1e30f;
        __syncthreads();

        if (kt + 1 < 32) {   // prefetch next tile into regs (overlaps compute)
            const uint4* nk = (const uint4*)(gK + (size_t)(kt + 1) * 64 * 64);
            const uint4* nv = (const uint4*)(gV + (kt + 1) * 64);
            kr0 = nk[0]; kr1 = nk[1];
            vr0 = nv[0]; vr1 = nv[1];
            if (tid < 64) mreg = mask[b * 2048 + (kt + 1) * 64 + tid];
        }

        float bv4[4];
        bf16x8 bk[4][2];
#pragma unroll
        for (int nt = 0; nt < 4; ++nt) {
            bv4[nt] = Biass[nt * 16 + l16];
            const bf16* kp = Ks + (nt * 16 + l16) * 72 + quad * 8;
            bk[nt][0] = *(const bf16x8*)kp;
            bk[nt][1] = *(const bf16x8*)(kp + 32);
        }

        // S = Q K^T, p = exp2(c + bias), write P tile (wave-private)
#pragma unroll
        for (int m = 0; m < 2; ++m) {
#pragma unroll
            for (int nt = 0; nt < 4; ++nt) {
                f32x4 c = {0.f, 0.f, 0.f, 0.f};
                c = mfma_bf16(aq[m][0], bk[nt][0], c);
                c = mfma_bf16(aq[m][1], bk[nt][1], c);
#pragma unroll
                for (int r = 0; r < 4; ++r) {
                    float p = __builtin_amdgcn_exp2f(c[r] + bv4[nt]);
                    myPs[(m * 16 + quad * 4 + r) * 72 + nt * 16 + l16] = __float2bfloat16(p);
                }
            }
        }

        // O += P V ; l += P @ ones
#pragma unroll
        for (int m = 0; m < 2; ++m) {
#pragma unroll
            for (int ks = 0; ks < 2; ++ks) {
                bf16x8 ap = *(const bf16x8*)(myPs + (m * 16 + l16) * 72 + ks * 32 + quad * 8);
                Lacc[m] = mfma_bf16(ap, ones, Lacc[m]);
#pragma unroll
                for (int nt = 0; nt < 4; ++nt) {
                    bf16x8 bvv = *(const bf16x8*)(Vs + (nt * 16 + l16) * 72 + ks * 32 + quad * 8);
                    O[m][nt] = mfma_bf16(ap, bvv, O[m][nt]);
                }
            }
        }
        __syncthreads();
    }

    // epilogue: O / l
#pragma unroll
    for (int m = 0; m < 2; ++m) {
        float inv[4];
#pragma unroll
        for (int r = 0; r < 4; ++r) inv[r] = __builtin_amdgcn_rcpf(Lacc[m][r]);
#pragma unroll
        for (int nt = 0; nt < 4; ++nt) {
#pragma unroll
            for (int r = 0; r < 4; ++r) {
                int row = q0 + wave * 32 + m * 16 + quad * 4 + r;
                Aout[((size_t)b * 2048 + row) * 1024 + h * 64 + nt * 16 + l16] =
                    __float2bfloat16(O[m][nt][r] * inv[r]);
            }
        }
    }
}

// ---------------- launcher ----------------
extern "C" void kernel_launch(void* const* d_in, const int* in_sizes, int n_in,
                              void* d_out, int out_size, void* d_ws, size_t ws_size,
                              hipStream_t stream) {
    const float* x     = (const float*)d_in[0];
    const float* gamma = (const float*)d_in[1];
    const int*   mask  = (const int*)d_in[2];
    const float* wqkv  = (const float*)d_in[3];
    const float* bqkv  = (const float*)d_in[4];
    const float* wo    = (const float*)d_in[5];
    const float* bo    = (const float*)d_in[6];
    float* out = (float*)d_out;

    char* ws = (char*)d_ws;
    const size_t MB = 1u << 20;
    bf16* xb    = (bf16*)(ws);            //  8 MB: x cast to bf16      [4096][1024]
    bf16* wqkvT = (bf16*)(ws + 8 * MB);   //  6 MB: W_qkv^T bf16        [3072][1024]
    bf16* woT   = (bf16*)(ws + 14 * MB);  //  2 MB: W_o^T bf16          [1024][1024]
    bf16* Qb    = (bf16*)(ws + 16 * MB);  //  8 MB: Q per head (scaled) [bh][s][dk]
    bf16* Kb    = (bf16*)(ws + 24 * MB);  //  8 MB: K per head          [bh][s][dk]
    bf16* Vt    = (bf16*)(ws + 32 * MB);  //  8 MB: V^T per head        [bh][dk][s]
    bf16* attn  = (bf16*)(ws + 40 * MB);  //  8 MB: attention out       [b*s][d]

    cast_bf16_kernel<<<4096, 256, 0, stream>>>(x, xb, 4194304 / 4);
    transpose_cast_kernel<<<dim3(96, 32), dim3(32, 8), 0, stream>>>(wqkv, wqkvT, 1024, 3072);
    transpose_cast_kernel<<<dim3(32, 32), dim3(32, 8), 0, stream>>>(wo, woT, 1024, 1024);

    // QKV GEMM: [4096,1024] x [1024,3072]
    gemm_bt_kernel<0><<<dim3(24, 32), 256, 0, stream>>>(
        xb, wqkvT, 4096, 3072, 1024, bqkv, nullptr, Qb, Kb, Vt, nullptr);

    // attention: grid (S/128, B*H)
    attn_kernel<<<dim3(16, 32), 256, 0, stream>>>(Qb, Kb, Vt, mask, attn);

    // out GEMM: [4096,1024] x [1024,1024], fused bias + (gamma+1)
    gemm_bt_kernel<1><<<dim3(8, 32), 256, 0, stream>>>(
        attn, woT, 4096, 1024, 1024, bo, gamma, nullptr, nullptr, nullptr, out);
}